// Round 1
// baseline (16305.203 us; speedup 1.0000x reference)
//
#include <hip/hip_runtime.h>

#define U_CNT 100001
#define I_CNT 50001
#define N_CNT 150002
#define DIM 64

// init: h0 = concat(user_emb, item_emb); acc = h0
__global__ void init_kernel(const float4* __restrict__ ue,
                            const float4* __restrict__ ie,
                            float4* __restrict__ h,
                            float4* __restrict__ acc) {
    int i = blockIdx.x * blockDim.x + threadIdx.x;   // over N_CNT*16 float4s
    if (i >= N_CNT * 16) return;
    float4 v = (i < U_CNT * 16) ? ue[i] : ie[i - U_CNT * 16];
    h[i] = v;
    acc[i] = v;
}

// atomic COO SpMM: y[r] += v * x[c], 16 threads per edge (float4 each)
__global__ void spmm_atomic(const int* __restrict__ rows,
                            const int* __restrict__ cols,
                            const float* __restrict__ vals,
                            const float4* __restrict__ x,
                            float* __restrict__ y,
                            int nnz) {
    int t = blockIdx.x * blockDim.x + threadIdx.x;   // over nnz*16
    if (t >= nnz * 16) return;
    int e = t >> 4;
    int s = t & 15;
    int r = rows[e];
    int c = cols[e];
    float v = vals[e];
    float4 xv = x[c * 16 + s];
    float* yp = y + (size_t)r * DIM + s * 4;
    atomicAdd(yp + 0, v * xv.x);
    atomicAdd(yp + 1, v * xv.y);
    atomicAdd(yp + 2, v * xv.z);
    atomicAdd(yp + 3, v * xv.w);
}

// acc += h; optionally scale by 0.25 on the last layer
__global__ void add_kernel(float4* __restrict__ acc,
                           const float4* __restrict__ h,
                           int do_scale) {
    int i = blockIdx.x * blockDim.x + threadIdx.x;
    if (i >= N_CNT * 16) return;
    float4 a = acc[i];
    float4 b = h[i];
    a.x += b.x; a.y += b.y; a.z += b.z; a.w += b.w;
    if (do_scale) {
        a.x *= 0.25f; a.y *= 0.25f; a.z *= 0.25f; a.w *= 0.25f;
    }
    acc[i] = a;
}

extern "C" void kernel_launch(void* const* d_in, const int* in_sizes, int n_in,
                              void* d_out, int out_size, void* d_ws, size_t ws_size,
                              hipStream_t stream) {
    const float* ue   = (const float*)d_in[0];
    const float* ie   = (const float*)d_in[1];
    const int*   rows = (const int*)d_in[2];
    const int*   cols = (const int*)d_in[3];
    const float* vals = (const float*)d_in[4];
    int nnz = in_sizes[2];

    float* acc = (float*)d_out;
    float* h0  = (float*)d_ws;
    float* h1  = h0 + (size_t)N_CNT * DIM;

    const int nvec = N_CNT * 16;                 // float4 count per [N,64] buffer
    const int tpb  = 256;

    init_kernel<<<(nvec + tpb - 1) / tpb, tpb, 0, stream>>>(
        (const float4*)ue, (const float4*)ie, (float4*)h0, (float4*)acc);

    float* cur = h0;
    float* nxt = h1;
    for (int l = 0; l < 3; ++l) {
        hipMemsetAsync(nxt, 0, (size_t)N_CNT * DIM * sizeof(float), stream);
        int total = nnz * 16;
        spmm_atomic<<<(total + tpb - 1) / tpb, tpb, 0, stream>>>(
            rows, cols, vals, (const float4*)cur, nxt, nnz);
        add_kernel<<<(nvec + tpb - 1) / tpb, tpb, 0, stream>>>(
            (float4*)acc, (const float4*)nxt, l == 2 ? 1 : 0);
        float* tmp = cur; cur = nxt; nxt = tmp;
    }
}

// Round 2
// 1787.020 us; speedup vs baseline: 9.1242x; 9.1242x over previous
//
#include <hip/hip_runtime.h>

#define U_CNT 100001
#define I_CNT 50001
#define N_CNT 150002
#define DIM 64
#define SCAN_T 1024

// init: h0 = concat(user_emb, item_emb); acc = h0
__global__ void init_kernel(const float4* __restrict__ ue,
                            const float4* __restrict__ ie,
                            float4* __restrict__ h,
                            float4* __restrict__ acc) {
    int i = blockIdx.x * blockDim.x + threadIdx.x;   // over N_CNT*16 float4s
    if (i >= N_CNT * 16) return;
    float4 v = (i < U_CNT * 16) ? ue[i] : ie[i - U_CNT * 16];
    h[i] = v;
    acc[i] = v;
}

// degree histogram
__global__ void hist_kernel(const int* __restrict__ rows, int* __restrict__ counts,
                            int nnz) {
    int i = blockIdx.x * blockDim.x + threadIdx.x;
    if (i >= nnz) return;
    atomicAdd(&counts[rows[i]], 1);
}

// single-block exclusive scan of counts[N_CNT] -> row_ptr[N_CNT+1], fill = copy
__global__ void scan_kernel(const int* __restrict__ counts,
                            int* __restrict__ row_ptr,
                            int* __restrict__ fill) {
    __shared__ int lds[SCAN_T];
    const int t = threadIdx.x;
    const int CH = (N_CNT + SCAN_T - 1) / SCAN_T;
    int b = t * CH;
    int e = b + CH; if (e > N_CNT) e = N_CNT;
    int s = 0;
    for (int i = b; i < e; ++i) s += counts[i];
    lds[t] = s;
    __syncthreads();
    // Hillis-Steele inclusive scan over SCAN_T chunk sums
    for (int off = 1; off < SCAN_T; off <<= 1) {
        int v = (t >= off) ? lds[t - off] : 0;
        __syncthreads();
        lds[t] += v;
        __syncthreads();
    }
    int run = (t == 0) ? 0 : lds[t - 1];
    for (int i = b; i < e; ++i) {
        int c = counts[i];
        row_ptr[i] = run;
        fill[i] = run;
        run += c;
    }
    if (t == 0) row_ptr[N_CNT] = lds[SCAN_T - 1];
}

// scatter edges into CSR order
__global__ void scatter_kernel(const int* __restrict__ rows,
                               const int* __restrict__ cols,
                               const float* __restrict__ vals,
                               int* __restrict__ fill,
                               int* __restrict__ col_s,
                               float* __restrict__ val_s,
                               int nnz) {
    int i = blockIdx.x * blockDim.x + threadIdx.x;
    if (i >= nnz) return;
    int r = rows[i];
    int p = atomicAdd(&fill[r], 1);
    col_s[p] = cols[i];
    val_s[p] = vals[i];
}

// gather SpMM: 16 lanes per row, float4 per lane. Fuses acc += y (and *0.25 last).
__global__ void spmm_gather(const int* __restrict__ row_ptr,
                            const int* __restrict__ col_s,
                            const float* __restrict__ val_s,
                            const float4* __restrict__ x,
                            float4* __restrict__ y,
                            float4* __restrict__ acc,
                            int last) {
    int r = blockIdx.x * 16 + (threadIdx.x >> 4);
    int s = threadIdx.x & 15;
    if (r >= N_CNT) return;
    int beg = row_ptr[r];
    int end = row_ptr[r + 1];
    float4 a; a.x = 0.f; a.y = 0.f; a.z = 0.f; a.w = 0.f;
    int j = beg;
    for (; j + 2 <= end; j += 2) {
        int   c0 = col_s[j];     int   c1 = col_s[j + 1];
        float v0 = val_s[j];     float v1 = val_s[j + 1];
        float4 x0 = x[(size_t)c0 * 16 + s];
        float4 x1 = x[(size_t)c1 * 16 + s];
        a.x += v0 * x0.x; a.y += v0 * x0.y; a.z += v0 * x0.z; a.w += v0 * x0.w;
        a.x += v1 * x1.x; a.y += v1 * x1.y; a.z += v1 * x1.z; a.w += v1 * x1.w;
    }
    if (j < end) {
        int   c0 = col_s[j];
        float v0 = val_s[j];
        float4 x0 = x[(size_t)c0 * 16 + s];
        a.x += v0 * x0.x; a.y += v0 * x0.y; a.z += v0 * x0.z; a.w += v0 * x0.w;
    }
    size_t o = (size_t)r * 16 + s;
    y[o] = a;
    float4 ac = acc[o];
    ac.x += a.x; ac.y += a.y; ac.z += a.z; ac.w += a.w;
    if (last) { ac.x *= 0.25f; ac.y *= 0.25f; ac.z *= 0.25f; ac.w *= 0.25f; }
    acc[o] = ac;
}

extern "C" void kernel_launch(void* const* d_in, const int* in_sizes, int n_in,
                              void* d_out, int out_size, void* d_ws, size_t ws_size,
                              hipStream_t stream) {
    const float* ue   = (const float*)d_in[0];
    const float* ie   = (const float*)d_in[1];
    const int*   rows = (const int*)d_in[2];
    const int*   cols = (const int*)d_in[3];
    const float* vals = (const float*)d_in[4];
    int nnz = in_sizes[2];

    float* acc = (float*)d_out;

    // workspace layout (all 16B-aligned by construction)
    float* h0      = (float*)d_ws;                       // N*64 floats
    float* h1      = h0 + (size_t)N_CNT * DIM;           // N*64 floats
    int*   counts  = (int*)(h1 + (size_t)N_CNT * DIM);   // N
    int*   row_ptr = counts + N_CNT;                     // N+1
    int*   fill    = row_ptr + (N_CNT + 1);              // N
    int*   col_s   = fill + N_CNT + 13;                  // pad to keep 16B align
    float* val_s   = (float*)(col_s + nnz);              // nnz

    const int nvec = N_CNT * 16;
    const int tpb  = 256;

    init_kernel<<<(nvec + tpb - 1) / tpb, tpb, 0, stream>>>(
        (const float4*)ue, (const float4*)ie, (float4*)h0, (float4*)acc);

    // ---- CSR build (rebuilt every call: ws is re-poisoned) ----
    hipMemsetAsync(counts, 0, (size_t)N_CNT * sizeof(int), stream);
    hist_kernel<<<(nnz + tpb - 1) / tpb, tpb, 0, stream>>>(rows, counts, nnz);
    scan_kernel<<<1, SCAN_T, 0, stream>>>(counts, row_ptr, fill);
    scatter_kernel<<<(nnz + tpb - 1) / tpb, tpb, 0, stream>>>(
        rows, cols, vals, fill, col_s, val_s, nnz);

    // ---- 3 propagation layers, acc fused ----
    float* cur = h0;
    float* nxt = h1;
    const int rows_per_block = tpb / 16;                 // 16
    const int gblocks = (N_CNT + rows_per_block - 1) / rows_per_block;
    for (int l = 0; l < 3; ++l) {
        spmm_gather<<<gblocks, tpb, 0, stream>>>(
            row_ptr, col_s, val_s, (const float4*)cur,
            (float4*)nxt, (float4*)acc, l == 2 ? 1 : 0);
        float* tmp = cur; cur = nxt; nxt = tmp;
    }
}